// Round 1
// baseline (348.798 us; speedup 1.0000x reference)
//
#include <hip/hip_runtime.h>

typedef unsigned short ushort_t;
typedef __attribute__((ext_vector_type(8))) short s16x8;   // 8 bf16 (4 VGPRs) MFMA A/B frag
typedef __attribute__((ext_vector_type(4))) float f32x4;   // 4 f32 MFMA C/D frag

#define B_PATHS 8192
#define NSTEP   30
#define DD      100
#define HH      110
#define TT      29            // number of subnets
#define ROWSTR  3000          // NSTEP*DD floats per path
#define LDK     136           // padded k-stride (bf16 elems) for act tiles; 272B rows
#define WFRAGSZ 14336         // per-stage frag-ordered W: 4 kb * 7 nt * 64 lanes * 8 elems
#define DT_C    (1.0f/30.0f)
#define R_C     0.05f
#define EPS_C   1e-3f

__device__ __forceinline__ ushort_t f2bf(float f) {  // RNE f32->bf16
  unsigned u = __float_as_uint(f);
  u = u + 0x7FFFu + ((u >> 16) & 1u);
  return (ushort_t)(u >> 16);
}
__device__ __forceinline__ float bf2f(ushort_t u) {
  return __uint_as_float(((unsigned)u) << 16);
}

// ---------------------------------------------------------------------------
// Prep: fold BN into weights/biases; emit W in MFMA B-fragment order:
//   elem j of chunk c=((kb*7+nt)*64+lane):  B[n=nt*16+(lane&15)][k=kb*32+(lane>>4)*8+j]
// so the subnet kernel loads B-frags straight from global (L2) with dwordx4.
// ---------------------------------------------------------------------------
__global__ void prep_kernel(const float* __restrict__ W1, const float* __restrict__ W2,
                            const float* __restrict__ W3,
                            const float* g0, const float* b0, const float* m0, const float* v0,
                            const float* g1, const float* b1, const float* m1, const float* v1,
                            const float* g2, const float* b2, const float* m2, const float* v2,
                            const float* g3, const float* b3, const float* m3, const float* v3,
                            ushort_t* __restrict__ wprep, float* __restrict__ bprep)
{
  const int mat = blockIdx.x, t = blockIdx.y, tid = threadIdx.x;
  __shared__ float wsh[110*110];
  __shared__ float sin_[112], hin_[112], sout_[112], hout_[112];

  int Kr, Nr; const float* W; const float *g, *bb, *mm, *vv;
  if (mat == 0)      { Kr = 100; Nr = 110; W = W1 + t*11000; g = g0+t*100; bb = b0+t*100; mm = m0+t*100; vv = v0+t*100; }
  else if (mat == 1) { Kr = 110; Nr = 110; W = W2 + t*12100; g = g1+t*110; bb = b1+t*110; mm = m1+t*110; vv = v1+t*110; }
  else               { Kr = 110; Nr = 100; W = W3 + t*11000; g = g2+t*110; bb = b2+t*110; mm = m2+t*110; vv = v2+t*110; }

  if (tid < Kr) {
    float s = g[tid] * rsqrtf(vv[tid] + EPS_C);
    sin_[tid] = s; hin_[tid] = bb[tid] - mm[tid]*s;
  }
  if (mat == 2 && tid < Nr) {
    float s = g3[t*100+tid] * rsqrtf(v3[t*100+tid] + EPS_C);
    sout_[tid] = s; hout_[tid] = b3[t*100+tid] - m3[t*100+tid]*s;
  }
  for (int i = tid; i < Kr*Nr; i += 256) wsh[i] = W[i];
  __syncthreads();

  if (tid < 128) {
    float c = 0.f;
    if (tid < Nr) {
      for (int k = 0; k < Kr; ++k) c += hin_[k] * wsh[k*Nr + tid];
      if (mat == 2) c = c * sout_[tid] + hout_[tid];
    }
    bprep[(t*3 + mat)*128 + tid] = c;
  }

  ushort_t* wo = wprep + (size_t)(t*3 + mat) * WFRAGSZ;
  for (int ch = tid; ch < 1792; ch += 256) {            // 1792 chunks of 8 elems
    const int lane = ch & 63, ntkb = ch >> 6;
    const int nt = ntkb % 7, kb = ntkb / 7;
    const int n  = nt*16 + (lane & 15);
    const int k0 = kb*32 + (lane >> 4)*8;
    ushort_t tmp[8];
#pragma unroll
    for (int j = 0; j < 8; ++j) {
      const int k = k0 + j;
      float v = 0.f;
      if (n < Nr && k < Kr) {
        v = sin_[k] * wsh[k*Nr + n];
        if (mat == 2) v *= sout_[n];
      }
      tmp[j] = f2bf(v);
    }
    ushort4 lo; lo.x = tmp[0]; lo.y = tmp[1]; lo.z = tmp[2]; lo.w = tmp[3];
    ushort4 hi; hi.x = tmp[4]; hi.y = tmp[5]; hi.z = tmp[6]; hi.w = tmp[7];
    *(ushort4*)(wo + ch*8)     = lo;
    *(ushort4*)(wo + ch*8 + 4) = hi;
  }
}

// ---------------------------------------------------------------------------
// One MLP stage, M=32 rows per wave, fully wave-private, IN-PLACE in act.
// All A-frag ds_reads complete (into regs) before any C ds_write; per-wave
// LDS ops are processed in order -> no barrier, no ping-pong buffer needed.
// B-frags straight from global (L2-resident, frag-ordered, dwordx4).
// ---------------------------------------------------------------------------
__device__ __forceinline__ void mlp_stage32(ushort_t* act, const ushort_t* __restrict__ wfrag,
                                            const float* __restrict__ biasg,
                                            int wrow, int lane, int lrow, int quad, bool relu)
{
  f32x4 acc[7][2];
  const f32x4 z4 = {0.f, 0.f, 0.f, 0.f};
#pragma unroll
  for (int nt = 0; nt < 7; ++nt) { acc[nt][0] = z4; acc[nt][1] = z4; }

#pragma unroll
  for (int kb = 0; kb < 4; ++kb) {
    const s16x8 a0 = *(const s16x8*)(act + (wrow      + lrow)*LDK + kb*32 + quad*8);
    const s16x8 a1 = *(const s16x8*)(act + (wrow + 16 + lrow)*LDK + kb*32 + quad*8);
    s16x8 b[7];
#pragma unroll
    for (int nt = 0; nt < 7; ++nt)
      b[nt] = *(const s16x8*)(wfrag + ((kb*7 + nt)*64 + lane)*8);
#pragma unroll
    for (int nt = 0; nt < 7; ++nt) {
      acc[nt][0] = __builtin_amdgcn_mfma_f32_16x16x32_bf16(a0, b[nt], acc[nt][0], 0, 0, 0);
      acc[nt][1] = __builtin_amdgcn_mfma_f32_16x16x32_bf16(a1, b[nt], acc[nt][1], 0, 0, 0);
    }
  }

#pragma unroll
  for (int nt = 0; nt < 7; ++nt) {
    const int col = nt*16 + lrow;
    const float bv = biasg[col];
#pragma unroll
    for (int mh = 0; mh < 2; ++mh) {
#pragma unroll
      for (int r = 0; r < 4; ++r) {
        float u = acc[nt][mh][r] + bv;        // C/D layout: row=quad*4+r, col=lane&15
        if (relu) u = u > 0.f ? u : 0.f;
        act[(wrow + mh*16 + quad*4 + r)*LDK + col] = f2bf(u);
      }
    }
  }
  // maintain zero pad cols [112,128) so next stage's K-sweep reads zeros
#pragma unroll
  for (int mh = 0; mh < 2; ++mh)
#pragma unroll
    for (int r = 0; r < 4; ++r)
      act[(wrow + mh*16 + quad*4 + r)*LDK + 112 + lrow] = 0;
}

// ---------------------------------------------------------------------------
// Fused subnet: block = (t, 64-row tile), 128 threads = 2 waves, each wave
// owns 32 rows end-to-end (stage-in, 3 MFMA stages, epilogue). NO barriers.
// ---------------------------------------------------------------------------
__global__ __launch_bounds__(128, 4)
void subnet_kernel(const float* __restrict__ X, const float* __restrict__ DW,
                   const float* __restrict__ sigmas,
                   const ushort_t* __restrict__ wprep, const float* __restrict__ bprep,
                   float* __restrict__ sbuf)
{
  __shared__ __align__(16) ushort_t act[64*LDK];      // 17408 B, single buffer

  const int tid  = threadIdx.x;
  const int t    = blockIdx.y;
  const int m0   = blockIdx.x * 64;
  const int lane = tid & 63;
  const int wrow = (tid >> 6) * 32;   // wave's 32-row slice
  const int lrow = lane & 15, quad = lane >> 4;

  // wave-private staging: X[:, t+1, :] rows [wrow,wrow+32) -> bf16, pad cols 100..127 = 0
  {
    const int c  = lane & 31;         // float4 group 0..31 (128 cols)
    const int r0 = lane >> 5;         // 0..1
#pragma unroll
    for (int i = 0; i < 16; ++i) {
      const int r = r0 + i*2;
      ushort4 u; u.x = 0; u.y = 0; u.z = 0; u.w = 0;
      if (c < 25) {
        const float4 v = *(const float4*)(X + (size_t)(m0 + wrow + r)*ROWSTR + (t+1)*DD + c*4);
        u.x = f2bf(v.x); u.y = f2bf(v.y); u.z = f2bf(v.z); u.w = f2bf(v.w);
      }
      *(ushort4*)(act + (wrow + r)*LDK + c*4) = u;
    }
  }
  // no __syncthreads: each wave reads/writes only its own 32 rows throughout

  const ushort_t* wf = wprep + (size_t)(t*3) * WFRAGSZ;
  const float*    bg = bprep + (t*3) * 128;

  mlp_stage32(act, wf,             bg,       wrow, lane, lrow, quad, true);
  mlp_stage32(act, wf + WFRAGSZ,   bg + 128, wrow, lane, lrow, quad, true);
  mlp_stage32(act, wf + 2*WFRAGSZ, bg + 256, wrow, lane, lrow, quad, false); // Z (bn3 folded)

  // epilogue: s[b] = sum_d sigma_d * X[b,xt,d] * Z[b,d] * DW[b,t+1,d]
  // 2 lanes per row, float4 loads; rows are this wave's own 32 rows
  {
    const int row  = wrow + (lane >> 1);
    const int part = lane & 1;
    const int b    = m0 + row;
    const int xt   = (t == TT - 1) ? (NSTEP - 2) : (t + 1);
    const float* xr = X  + (size_t)b*ROWSTR + xt*DD;
    const float* dr = DW + (size_t)b*ROWSTR + (t+1)*DD;
    float p = 0.f;
#pragma unroll
    for (int g = part; g < 25; g += 2) {
      const float4 xv = *(const float4*)(xr + g*4);
      const float4 dv = *(const float4*)(dr + g*4);
      const float4 sg = *(const float4*)(sigmas + g*4);
      const ushort4 zu = *(const ushort4*)(act + row*LDK + g*4);
      p += sg.x*xv.x*dv.x*bf2f(zu.x);
      p += sg.y*xv.y*dv.y*bf2f(zu.y);
      p += sg.z*xv.z*dv.z*bf2f(zu.z);
      p += sg.w*xv.w*dv.w*bf2f(zu.w);
    }
    p += __shfl_xor(p, 1, 64);
    if (part == 0)
      sbuf[(size_t)(t+1)*B_PATHS + b] = p;
  }
}

// ---------------------------------------------------------------------------
// Y recursion: y = y + R*y*DT + s_tau, tau = 0..29 ; s_0 uses z_init.
// 4 lanes per path (64B-coalesced groups), 64 paths/block -> 128 blocks.
// ---------------------------------------------------------------------------
__global__ __launch_bounds__(256)
void y_kernel(const float* __restrict__ X, const float* __restrict__ DW,
              const float* __restrict__ sigmas, const float* __restrict__ y_init,
              const float* __restrict__ z_init, const float* __restrict__ sbuf,
              float* __restrict__ out)
{
  const int tid  = threadIdx.x;
  const int row  = tid >> 2, part = tid & 3;
  const int b    = blockIdx.x * 64 + row;
  const float* xr = X + (size_t)b * ROWSTR;   // step 0
  const float* dr = DW + (size_t)b * ROWSTR;
  float p = 0.f;
#pragma unroll
  for (int g = part; g < 25; g += 4) {
    const float4 xv = *(const float4*)(xr + g*4);
    const float4 dv = *(const float4*)(dr + g*4);
    const float4 sg = *(const float4*)(sigmas + g*4);
    const float4 zv = *(const float4*)(z_init + g*4);
    p += sg.x*xv.x*zv.x*dv.x;
    p += sg.y*xv.y*zv.y*dv.y;
    p += sg.z*xv.z*zv.z*dv.z;
    p += sg.w*xv.w*zv.w*dv.w;
  }
  p += __shfl_xor(p, 1, 64);
  p += __shfl_xor(p, 2, 64);
  if (part == 0) {
    float y = y_init[0];
    y = y + R_C*y*DT_C + p;
#pragma unroll
    for (int tau = 1; tau < NSTEP; ++tau)
      y = y + R_C*y*DT_C + sbuf[(size_t)tau*B_PATHS + b];
    out[b] = y;
  }
}

extern "C" void kernel_launch(void* const* d_in, const int* in_sizes, int n_in,
                              void* d_out, int out_size, void* d_ws, size_t ws_size,
                              hipStream_t stream) {
  const float* X      = (const float*)d_in[0];
  const float* DWs    = (const float*)d_in[1];
  const float* sigmas = (const float*)d_in[2];
  const float* y_init = (const float*)d_in[3];
  const float* z_init = (const float*)d_in[4];
  const float* W1     = (const float*)d_in[5];
  const float* W2     = (const float*)d_in[6];
  const float* W3     = (const float*)d_in[7];
  const float* bn[16];
  for (int i = 0; i < 16; ++i) bn[i] = (const float*)d_in[8 + i];

  char* ws = (char*)d_ws;
  ushort_t* wprep = (ushort_t*)ws;                     // 87*14336*2 = 2,494,464 B
  float*    bprep = (float*)(ws + 2494464);            // 87*128*4   =    44,544 B
  float*    sbuf  = (float*)(ws + 2539008);            // 30*8192*4  =   983,040 B
  float*    out   = (float*)d_out;

  prep_kernel<<<dim3(3, TT), 256, 0, stream>>>(
      W1, W2, W3,
      bn[0], bn[1], bn[2], bn[3],  bn[4], bn[5], bn[6], bn[7],
      bn[8], bn[9], bn[10], bn[11], bn[12], bn[13], bn[14], bn[15],
      wprep, bprep);
  subnet_kernel<<<dim3(B_PATHS/64, TT), 128, 0, stream>>>(
      X, DWs, sigmas, wprep, bprep, sbuf);
  y_kernel<<<dim3(B_PATHS/64), 256, 0, stream>>>(
      X, DWs, sigmas, y_init, z_init, sbuf, out);
}

// Round 2
// 344.312 us; speedup vs baseline: 1.0130x; 1.0130x over previous
//
#include <hip/hip_runtime.h>

typedef unsigned short ushort_t;
typedef __attribute__((ext_vector_type(8))) short s16x8;   // 8 bf16 (4 VGPRs) MFMA A/B frag
typedef __attribute__((ext_vector_type(4))) float f32x4;   // 4 f32 MFMA C/D frag

#define B_PATHS 8192
#define NSTEP   30
#define DD      100
#define HH      110
#define TT      29            // number of subnets
#define ROWSTR  3000          // NSTEP*DD floats per path
#define LDK     136           // padded k-stride (bf16 elems) for act tiles; 272B rows
#define WFRAGSZ 14336         // per-stage frag-ordered W: 4 kb * 7 nt * 64 lanes * 8 elems
#define DT_C    (1.0f/30.0f)
#define R_C     0.05f
#define EPS_C   1e-3f

__device__ __forceinline__ ushort_t f2bf(float f) {  // RNE f32->bf16
  unsigned u = __float_as_uint(f);
  u = u + 0x7FFFu + ((u >> 16) & 1u);
  return (ushort_t)(u >> 16);
}
__device__ __forceinline__ float bf2f(ushort_t u) {
  return __uint_as_float(((unsigned)u) << 16);
}

// ---------------------------------------------------------------------------
// Prep: fold BN into weights/biases; emit W in MFMA B-fragment order:
//   elem j of chunk c=((kb*7+nt)*64+lane):  B[n=nt*16+(lane&15)][k=kb*32+(lane>>4)*8+j]
// so the subnet kernel loads B-frags straight from global (L2) with dwordx4.
// ---------------------------------------------------------------------------
__global__ void prep_kernel(const float* __restrict__ W1, const float* __restrict__ W2,
                            const float* __restrict__ W3,
                            const float* g0, const float* b0, const float* m0, const float* v0,
                            const float* g1, const float* b1, const float* m1, const float* v1,
                            const float* g2, const float* b2, const float* m2, const float* v2,
                            const float* g3, const float* b3, const float* m3, const float* v3,
                            ushort_t* __restrict__ wprep, float* __restrict__ bprep)
{
  const int mat = blockIdx.x, t = blockIdx.y, tid = threadIdx.x;
  __shared__ __align__(16) float wsh[110*110];
  __shared__ float sin_[112], hin_[112], sout_[112], hout_[112];

  int Kr, Nr; const float* W; const float *g, *bb, *mm, *vv;
  if (mat == 0)      { Kr = 100; Nr = 110; W = W1 + t*11000; g = g0+t*100; bb = b0+t*100; mm = m0+t*100; vv = v0+t*100; }
  else if (mat == 1) { Kr = 110; Nr = 110; W = W2 + t*12100; g = g1+t*110; bb = b1+t*110; mm = m1+t*110; vv = v1+t*110; }
  else               { Kr = 110; Nr = 100; W = W3 + t*11000; g = g2+t*110; bb = b2+t*110; mm = m2+t*110; vv = v2+t*110; }

  if (tid < Kr) {
    float s = g[tid] * rsqrtf(vv[tid] + EPS_C);
    sin_[tid] = s; hin_[tid] = bb[tid] - mm[tid]*s;
  }
  if (mat == 2 && tid < Nr) {
    float s = g3[t*100+tid] * rsqrtf(v3[t*100+tid] + EPS_C);
    sout_[tid] = s; hout_[tid] = b3[t*100+tid] - m3[t*100+tid]*s;
  }
  // float4 staging of W tile (Kr*Nr is always divisible by 4)
  {
    const int n4 = (Kr*Nr) >> 2;
    for (int i = tid; i < n4; i += 256)
      ((float4*)wsh)[i] = ((const float4*)W)[i];
  }
  __syncthreads();

  if (tid < 128) {
    float c = 0.f;
    if (tid < Nr) {
      for (int k = 0; k < Kr; ++k) c += hin_[k] * wsh[k*Nr + tid];
      if (mat == 2) c = c * sout_[tid] + hout_[tid];
    }
    bprep[(t*3 + mat)*128 + tid] = c;
  }

  ushort_t* wo = wprep + (size_t)(t*3 + mat) * WFRAGSZ;
  for (int ch = tid; ch < 1792; ch += 256) {            // 1792 chunks of 8 elems
    const int lane = ch & 63, ntkb = ch >> 6;
    const int nt = ntkb % 7, kb = ntkb / 7;
    const int n  = nt*16 + (lane & 15);
    const int k0 = kb*32 + (lane >> 4)*8;
    ushort_t tmp[8];
#pragma unroll
    for (int j = 0; j < 8; ++j) {
      const int k = k0 + j;
      float v = 0.f;
      if (n < Nr && k < Kr) {
        v = sin_[k] * wsh[k*Nr + n];
        if (mat == 2) v *= sout_[n];
      }
      tmp[j] = f2bf(v);
    }
    ushort4 lo; lo.x = tmp[0]; lo.y = tmp[1]; lo.z = tmp[2]; lo.w = tmp[3];
    ushort4 hi; hi.x = tmp[4]; hi.y = tmp[5]; hi.z = tmp[6]; hi.w = tmp[7];
    *(ushort4*)(wo + ch*8)     = lo;
    *(ushort4*)(wo + ch*8 + 4) = hi;
  }
}

// ---------------------------------------------------------------------------
// One MLP stage, M=16 rows per wave, fully wave-private, IN-PLACE in act.
// All A-frag ds_reads complete (into regs) before any C ds_write; per-wave
// LDS ops are in order -> no barrier, no ping-pong buffer needed.
// B-frags straight from global (L2-resident, frag-ordered, dwordx4).
// ---------------------------------------------------------------------------
__device__ __forceinline__ void mlp_stage16(ushort_t* act, const ushort_t* __restrict__ wfrag,
                                            const float* __restrict__ biasg,
                                            int wrow, int lane, int lrow, int quad, bool relu)
{
  f32x4 acc[7];
  const f32x4 z4 = {0.f, 0.f, 0.f, 0.f};
#pragma unroll
  for (int nt = 0; nt < 7; ++nt) acc[nt] = z4;

  s16x8 a[4];
#pragma unroll
  for (int kb = 0; kb < 4; ++kb)
    a[kb] = *(const s16x8*)(act + (wrow + lrow)*LDK + kb*32 + quad*8);

#pragma unroll
  for (int kb = 0; kb < 4; ++kb) {
    s16x8 b[7];
#pragma unroll
    for (int nt = 0; nt < 7; ++nt)
      b[nt] = *(const s16x8*)(wfrag + ((kb*7 + nt)*64 + lane)*8);
#pragma unroll
    for (int nt = 0; nt < 7; ++nt)
      acc[nt] = __builtin_amdgcn_mfma_f32_16x16x32_bf16(a[kb], b[nt], acc[nt], 0, 0, 0);
  }

#pragma unroll
  for (int nt = 0; nt < 7; ++nt) {
    const int col = nt*16 + lrow;
    const float bv = biasg[col];
#pragma unroll
    for (int r = 0; r < 4; ++r) {
      float u = acc[nt][r] + bv;              // C/D layout: row=quad*4+r, col=lane&15
      if (relu) u = u > 0.f ? u : 0.f;
      act[(wrow + quad*4 + r)*LDK + col] = f2bf(u);
    }
  }
  // maintain zero pad cols [112,128) so next stage's K-sweep reads zeros
#pragma unroll
  for (int r = 0; r < 4; ++r)
    act[(wrow + quad*4 + r)*LDK + 112 + lrow] = 0;
}

// ---------------------------------------------------------------------------
// Fused subnet: block = (t, 32-row tile), 128 threads = 2 waves, each wave
// owns 16 rows end-to-end (stage-in, 3 MFMA stages, epilogue). NO barriers.
// Grid = (8192/32, 29) = 7424 blocks -> ~58 waves/CU of supply; VGPR<=64 and
// LDS 8704B allow the full 32-wave/CU slot limit.
// ---------------------------------------------------------------------------
__global__ __launch_bounds__(128, 8)
void subnet_kernel(const float* __restrict__ X, const float* __restrict__ DW,
                   const float* __restrict__ sigmas,
                   const ushort_t* __restrict__ wprep, const float* __restrict__ bprep,
                   float* __restrict__ sbuf)
{
  __shared__ __align__(16) ushort_t act[32*LDK];      // 8704 B, single buffer

  const int tid  = threadIdx.x;
  const int t    = blockIdx.y;
  const int m0   = blockIdx.x * 32;
  const int lane = tid & 63;
  const int wrow = (tid >> 6) * 16;   // wave's private 16-row slice
  const int lrow = lane & 15, quad = lane >> 4;

  // wave-private staging: X[:, t+1, :] rows [wrow,wrow+16) -> bf16, pad cols 100..127 = 0
  {
    const int c  = lane & 31;         // float4 group 0..31 (128 cols)
    const int r0 = lane >> 5;         // 0..1
#pragma unroll
    for (int i = 0; i < 8; ++i) {
      const int r = r0 + i*2;
      ushort4 u; u.x = 0; u.y = 0; u.z = 0; u.w = 0;
      if (c < 25) {
        const float4 v = *(const float4*)(X + (size_t)(m0 + wrow + r)*ROWSTR + (t+1)*DD + c*4);
        u.x = f2bf(v.x); u.y = f2bf(v.y); u.z = f2bf(v.z); u.w = f2bf(v.w);
      }
      *(ushort4*)(act + (wrow + r)*LDK + c*4) = u;
    }
  }
  // no __syncthreads: each wave reads/writes only its own 16 rows throughout

  const ushort_t* wf = wprep + (size_t)(t*3) * WFRAGSZ;
  const float*    bg = bprep + (t*3) * 128;

  mlp_stage16(act, wf,             bg,       wrow, lane, lrow, quad, true);
  mlp_stage16(act, wf + WFRAGSZ,   bg + 128, wrow, lane, lrow, quad, true);
  mlp_stage16(act, wf + 2*WFRAGSZ, bg + 256, wrow, lane, lrow, quad, false); // Z (bn3 folded)

  // epilogue: s[b] = sum_d sigma_d * X[b,xt,d] * Z[b,d] * DW[b,t+1,d]
  // 4 lanes per row, float4 loads; rows are this wave's own 16 rows
  {
    const int row  = wrow + (lane >> 2);
    const int part = lane & 3;
    const int b    = m0 + row;
    const int xt   = (t == TT - 1) ? (NSTEP - 2) : (t + 1);
    const float* xr = X  + (size_t)b*ROWSTR + xt*DD;
    const float* dr = DW + (size_t)b*ROWSTR + (t+1)*DD;
    float p = 0.f;
#pragma unroll
    for (int g = part; g < 25; g += 4) {
      const float4 xv = *(const float4*)(xr + g*4);
      const float4 dv = *(const float4*)(dr + g*4);
      const float4 sg = *(const float4*)(sigmas + g*4);
      const ushort4 zu = *(const ushort4*)(act + row*LDK + g*4);
      p += sg.x*xv.x*dv.x*bf2f(zu.x);
      p += sg.y*xv.y*dv.y*bf2f(zu.y);
      p += sg.z*xv.z*dv.z*bf2f(zu.z);
      p += sg.w*xv.w*dv.w*bf2f(zu.w);
    }
    p += __shfl_xor(p, 1, 64);
    p += __shfl_xor(p, 2, 64);
    if (part == 0)
      sbuf[(size_t)(t+1)*B_PATHS + b] = p;
  }
}

// ---------------------------------------------------------------------------
// Y recursion, linearized:  y_final = y_init*G^30 + sum_tau s_tau * G^(29-tau)
// with G = 1 + R*DT; s_0 from z_init (computed here), s_1..s_29 from sbuf.
// 8 lanes per path, 32 paths/block -> 256 blocks (1/CU) for latency hiding.
// ---------------------------------------------------------------------------
__global__ __launch_bounds__(256)
void y_kernel(const float* __restrict__ X, const float* __restrict__ DW,
              const float* __restrict__ sigmas, const float* __restrict__ y_init,
              const float* __restrict__ z_init, const float* __restrict__ sbuf,
              float* __restrict__ out)
{
  const int tid  = threadIdx.x;
  const int row  = tid >> 3, part = tid & 7;   // 32 paths per block
  const int b    = blockIdx.x * 32 + row;
  const float* xr = X + (size_t)b * ROWSTR;   // step 0
  const float* dr = DW + (size_t)b * ROWSTR;
  float p = 0.f;
#pragma unroll
  for (int g = part; g < 25; g += 8) {
    const float4 xv = *(const float4*)(xr + g*4);
    const float4 dv = *(const float4*)(dr + g*4);
    const float4 sg = *(const float4*)(sigmas + g*4);
    const float4 zv = *(const float4*)(z_init + g*4);
    p += sg.x*xv.x*zv.x*dv.x;
    p += sg.y*xv.y*zv.y*dv.y;
    p += sg.z*xv.z*zv.z*dv.z;
    p += sg.w*xv.w*zv.w*dv.w;
  }
  p += __shfl_xor(p, 1, 64);
  p += __shfl_xor(p, 2, 64);
  p += __shfl_xor(p, 4, 64);

  const float G = 1.f + R_C*DT_C;
  float ss = 0.f;
#pragma unroll
  for (int tau = 1 + part; tau < NSTEP; tau += 8)
    ss += sbuf[(size_t)tau*B_PATHS + b] * __powf(G, (float)(NSTEP - 1 - tau));
  ss += __shfl_xor(ss, 1, 64);
  ss += __shfl_xor(ss, 2, 64);
  ss += __shfl_xor(ss, 4, 64);

  if (part == 0)
    out[b] = y_init[0]*__powf(G, 30.f) + p*__powf(G, 29.f) + ss;
}

extern "C" void kernel_launch(void* const* d_in, const int* in_sizes, int n_in,
                              void* d_out, int out_size, void* d_ws, size_t ws_size,
                              hipStream_t stream) {
  const float* X      = (const float*)d_in[0];
  const float* DWs    = (const float*)d_in[1];
  const float* sigmas = (const float*)d_in[2];
  const float* y_init = (const float*)d_in[3];
  const float* z_init = (const float*)d_in[4];
  const float* W1     = (const float*)d_in[5];
  const float* W2     = (const float*)d_in[6];
  const float* W3     = (const float*)d_in[7];
  const float* bn[16];
  for (int i = 0; i < 16; ++i) bn[i] = (const float*)d_in[8 + i];

  char* ws = (char*)d_ws;
  ushort_t* wprep = (ushort_t*)ws;                     // 87*14336*2 = 2,494,464 B
  float*    bprep = (float*)(ws + 2494464);            // 87*128*4   =    44,544 B
  float*    sbuf  = (float*)(ws + 2539008);            // 30*8192*4  =   983,040 B
  float*    out   = (float*)d_out;

  prep_kernel<<<dim3(3, TT), 256, 0, stream>>>(
      W1, W2, W3,
      bn[0], bn[1], bn[2], bn[3],  bn[4], bn[5], bn[6], bn[7],
      bn[8], bn[9], bn[10], bn[11], bn[12], bn[13], bn[14], bn[15],
      wprep, bprep);
  subnet_kernel<<<dim3(B_PATHS/32, TT), 128, 0, stream>>>(
      X, DWs, sigmas, wprep, bprep, sbuf);
  y_kernel<<<dim3(B_PATHS/32), 256, 0, stream>>>(
      X, DWs, sigmas, y_init, z_init, sbuf, out);
}

// Round 4
// 322.168 us; speedup vs baseline: 1.0827x; 1.0687x over previous
//
#include <hip/hip_runtime.h>

typedef unsigned short ushort_t;
typedef __attribute__((ext_vector_type(8))) short s16x8;   // 8 bf16 (4 VGPRs) MFMA A/B frag
typedef __attribute__((ext_vector_type(4))) float f32x4;   // 4 f32 MFMA C/D frag

#define B_PATHS 8192
#define NSTEP   30
#define DD      100
#define HH      110
#define TT      29            // number of subnets
#define ROWSTR  3000          // NSTEP*DD floats per path
#define LDK     136           // padded k-stride (bf16 elems) for act tiles; 272B rows
#define WFRAGSZ 14336         // per-stage frag-ordered W: 4 kb * 7 nt * 64 lanes * 8 elems
#define DT_C    (1.0f/30.0f)
#define R_C     0.05f
#define EPS_C   1e-3f

__device__ __forceinline__ ushort_t f2bf(float f) {  // RNE f32->bf16
  unsigned u = __float_as_uint(f);
  u = u + 0x7FFFu + ((u >> 16) & 1u);
  return (ushort_t)(u >> 16);
}
__device__ __forceinline__ float bf2f(ushort_t u) {
  return __uint_as_float(((unsigned)u) << 16);
}

// ---------------------------------------------------------------------------
// Prep: fold BN into weights/biases; emit W in MFMA B-fragment order:
//   elem j of chunk c=((kb*7+nt)*64+lane):  B[n=nt*16+(lane&15)][k=kb*32+(lane>>4)*8+j]
// so the subnet kernel stages W tiles with perfectly-coalesced 16B loads.
// ---------------------------------------------------------------------------
__global__ void prep_kernel(const float* __restrict__ W1, const float* __restrict__ W2,
                            const float* __restrict__ W3,
                            const float* g0, const float* b0, const float* m0, const float* v0,
                            const float* g1, const float* b1, const float* m1, const float* v1,
                            const float* g2, const float* b2, const float* m2, const float* v2,
                            const float* g3, const float* b3, const float* m3, const float* v3,
                            ushort_t* __restrict__ wprep, float* __restrict__ bprep)
{
  const int mat = blockIdx.x, t = blockIdx.y, tid = threadIdx.x;
  __shared__ __align__(16) float wsh[110*110];
  __shared__ float sin_[112], hin_[112], sout_[112], hout_[112];

  int Kr, Nr; const float* W; const float *g, *bb, *mm, *vv;
  if (mat == 0)      { Kr = 100; Nr = 110; W = W1 + t*11000; g = g0+t*100; bb = b0+t*100; mm = m0+t*100; vv = v0+t*100; }
  else if (mat == 1) { Kr = 110; Nr = 110; W = W2 + t*12100; g = g1+t*110; bb = b1+t*110; mm = m1+t*110; vv = v1+t*110; }
  else               { Kr = 110; Nr = 100; W = W3 + t*11000; g = g2+t*110; bb = b2+t*110; mm = m2+t*110; vv = v2+t*110; }

  if (tid < Kr) {
    float s = g[tid] * rsqrtf(vv[tid] + EPS_C);
    sin_[tid] = s; hin_[tid] = bb[tid] - mm[tid]*s;
  }
  if (mat == 2 && tid < Nr) {
    float s = g3[t*100+tid] * rsqrtf(v3[t*100+tid] + EPS_C);
    sout_[tid] = s; hout_[tid] = b3[t*100+tid] - m3[t*100+tid]*s;
  }
  // float4 staging of W tile (Kr*Nr is always divisible by 4)
  {
    const int n4 = (Kr*Nr) >> 2;
    for (int i = tid; i < n4; i += 256)
      ((float4*)wsh)[i] = ((const float4*)W)[i];
  }
  __syncthreads();

  if (tid < 128) {
    float c = 0.f;
    if (tid < Nr) {
      for (int k = 0; k < Kr; ++k) c += hin_[k] * wsh[k*Nr + tid];
      if (mat == 2) c = c * sout_[tid] + hout_[tid];
    }
    bprep[(t*3 + mat)*128 + tid] = c;
  }

  ushort_t* wo = wprep + (size_t)(t*3 + mat) * WFRAGSZ;
  for (int ch = tid; ch < 1792; ch += 256) {            // 1792 chunks of 8 elems
    const int lane = ch & 63, ntkb = ch >> 6;
    const int nt = ntkb % 7, kb = ntkb / 7;
    const int n  = nt*16 + (lane & 15);
    const int k0 = kb*32 + (lane >> 4)*8;
    ushort_t tmp[8];
#pragma unroll
    for (int j = 0; j < 8; ++j) {
      const int k = k0 + j;
      float v = 0.f;
      if (n < Nr && k < Kr) {
        v = sin_[k] * wsh[k*Nr + n];
        if (mat == 2) v *= sout_[n];
      }
      tmp[j] = f2bf(v);
    }
    ushort4 lo; lo.x = tmp[0]; lo.y = tmp[1]; lo.z = tmp[2]; lo.w = tmp[3];
    ushort4 hi; hi.x = tmp[4]; hi.y = tmp[5]; hi.z = tmp[6]; hi.w = tmp[7];
    *(ushort4*)(wo + ch*8)     = lo;
    *(ushort4*)(wo + ch*8 + 4) = hi;
  }
}

// ---------------------------------------------------------------------------
// One MLP stage, M=16 rows per wave, act wave-private IN-PLACE; B-frags from
// LDS wbuf (shared by all 4 waves). ds_read_b128 of contiguous 1KB rows ->
// conflict-free, ~120cy latency vs ~800cy L3. b[7] batches pipeline vs MFMA.
// ---------------------------------------------------------------------------
__device__ __forceinline__ void mlp_stage16(ushort_t* act, const ushort_t* wbuf,
                                            const float* __restrict__ biasg,
                                            int wrow, int lane, int lrow, int quad, bool relu)
{
  f32x4 acc[7];
  const f32x4 z4 = {0.f, 0.f, 0.f, 0.f};
#pragma unroll
  for (int nt = 0; nt < 7; ++nt) acc[nt] = z4;

  s16x8 a[4];
#pragma unroll
  for (int kb = 0; kb < 4; ++kb)
    a[kb] = *(const s16x8*)(act + (wrow + lrow)*LDK + kb*32 + quad*8);

#pragma unroll
  for (int kb = 0; kb < 4; ++kb) {
    s16x8 b[7];
#pragma unroll
    for (int nt = 0; nt < 7; ++nt)
      b[nt] = *(const s16x8*)(wbuf + ((kb*7 + nt)*64 + lane)*8);
#pragma unroll
    for (int nt = 0; nt < 7; ++nt)
      acc[nt] = __builtin_amdgcn_mfma_f32_16x16x32_bf16(a[kb], b[nt], acc[nt], 0, 0, 0);
  }

#pragma unroll
  for (int nt = 0; nt < 7; ++nt) {
    const int col = nt*16 + lrow;
    const float bv = biasg[col];
#pragma unroll
    for (int r = 0; r < 4; ++r) {
      float u = acc[nt][r] + bv;              // C/D layout: row=quad*4+r, col=lane&15
      if (relu) u = u > 0.f ? u : 0.f;
      act[(wrow + quad*4 + r)*LDK + col] = f2bf(u);
    }
  }
  // maintain zero pad cols [112,128) so next stage's K-sweep reads zeros
#pragma unroll
  for (int r = 0; r < 4; ++r)
    act[(wrow + quad*4 + r)*LDK + 112 + lrow] = 0;
}

// ---------------------------------------------------------------------------
// Fused subnet: block = (t, 64-row tile), 256 threads = 4 waves x 16 rows.
// Per-stage W staged global->reg->LDS with issue-early/write-late split so
// W latency hides under the previous stage's compute. LDS 46080B -> 3 blk/CU.
// ---------------------------------------------------------------------------
__global__ __launch_bounds__(256, 3)
void subnet_kernel(const float* __restrict__ X, const float* __restrict__ DW,
                   const float* __restrict__ sigmas,
                   const ushort_t* __restrict__ wprep, const float* __restrict__ bprep,
                   float* __restrict__ sbuf)
{
  __shared__ __align__(16) ushort_t act[64*LDK];      // 17408 B
  __shared__ __align__(16) ushort_t wbuf[WFRAGSZ];    // 28672 B  (total 46080 B)

  const int tid  = threadIdx.x;
  const int t    = blockIdx.y;
  const int m0   = blockIdx.x * 64;
  const int lane = tid & 63;
  const int wrow = (tid >> 6) * 16;   // wave's private 16-row slice
  const int lrow = lane & 15, quad = lane >> 4;

  const ushort_t* wf = wprep + (size_t)(t*3) * WFRAGSZ;
  const float*    bg = bprep + (t*3) * 128;

  // ---- issue W0 loads (16B/thread x 7 -> 28672B), latency overlaps X staging
  s16x8 wst[7];
#pragma unroll
  for (int j = 0; j < 7; ++j)
    wst[j] = *(const s16x8*)(wf + (j*256 + tid)*8);

  // ---- block-wide X staging: X[:, t+1, :] -> bf16 act, pad cols 100..127 = 0
  for (int jj = tid; jj < 64*32; jj += 256) {
    const int r = jj >> 5, c = jj & 31;        // c = float4 group (128 cols)
    ushort4 u; u.x = 0; u.y = 0; u.z = 0; u.w = 0;
    if (c < 25) {
      const float4 v = *(const float4*)(X + (size_t)(m0 + r)*ROWSTR + (t+1)*DD + c*4);
      u.x = f2bf(v.x); u.y = f2bf(v.y); u.z = f2bf(v.z); u.w = f2bf(v.w);
    }
    *(ushort4*)(act + r*LDK + c*4) = u;
  }

  // ---- write W0, barrier (covers act staging too)
#pragma unroll
  for (int j = 0; j < 7; ++j)
    *(s16x8*)(wbuf + (j*256 + tid)*8) = wst[j];
  __syncthreads();                                   // W0 + act visible

  // ---- stage 0 (issue W1 first so its latency hides under compute)
#pragma unroll
  for (int j = 0; j < 7; ++j)
    wst[j] = *(const s16x8*)(wf + WFRAGSZ + (j*256 + tid)*8);
  mlp_stage16(act, wbuf, bg, wrow, lane, lrow, quad, true);
  __syncthreads();                                   // all waves done reading W0
#pragma unroll
  for (int j = 0; j < 7; ++j)
    *(s16x8*)(wbuf + (j*256 + tid)*8) = wst[j];
  __syncthreads();                                   // W1 visible

  // ---- stage 1 (issue W2 first)
#pragma unroll
  for (int j = 0; j < 7; ++j)
    wst[j] = *(const s16x8*)(wf + 2*WFRAGSZ + (j*256 + tid)*8);
  mlp_stage16(act, wbuf, bg + 128, wrow, lane, lrow, quad, true);
  __syncthreads();                                   // done reading W1
#pragma unroll
  for (int j = 0; j < 7; ++j)
    *(s16x8*)(wbuf + (j*256 + tid)*8) = wst[j];
  __syncthreads();                                   // W2 visible

  // ---- stage 2: Z (bn3 folded)
  mlp_stage16(act, wbuf, bg + 256, wrow, lane, lrow, quad, false);

  // ---- epilogue: s[b] = sum_d sigma_d * X[b,xt,d] * Z[b,d] * DW[b,t+1,d]
  // 4 lanes per row; rows are this wave's own 16 rows (it wrote them in stage 2)
  {
    const int row  = wrow + (lane >> 2);
    const int part = lane & 3;
    const int b    = m0 + row;
    const int xt   = (t == TT - 1) ? (NSTEP - 2) : (t + 1);
    const float* xr = X  + (size_t)b*ROWSTR + xt*DD;
    const float* dr = DW + (size_t)b*ROWSTR + (t+1)*DD;
    float p = 0.f;
#pragma unroll
    for (int g = part; g < 25; g += 4) {
      const float4 xv = *(const float4*)(xr + g*4);
      const float4 dv = *(const float4*)(dr + g*4);
      const float4 sg = *(const float4*)(sigmas + g*4);
      const ushort4 zu = *(const ushort4*)(act + row*LDK + g*4);
      p += sg.x*xv.x*dv.x*bf2f(zu.x);
      p += sg.y*xv.y*dv.y*bf2f(zu.y);
      p += sg.z*xv.z*dv.z*bf2f(zu.z);
      p += sg.w*xv.w*dv.w*bf2f(zu.w);
    }
    p += __shfl_xor(p, 1, 64);
    p += __shfl_xor(p, 2, 64);
    if (part == 0)
      sbuf[(size_t)(t+1)*B_PATHS + b] = p;
  }
}

// ---------------------------------------------------------------------------
// Y recursion, linearized:  y_final = y_init*G^30 + sum_tau s_tau * G^(29-tau)
// with G = 1 + R*DT; s_0 from z_init (computed here), s_1..s_29 from sbuf.
// 8 lanes per path, 32 paths/block -> 256 blocks (1/CU) for latency hiding.
// ---------------------------------------------------------------------------
__global__ __launch_bounds__(256)
void y_kernel(const float* __restrict__ X, const float* __restrict__ DW,
              const float* __restrict__ sigmas, const float* __restrict__ y_init,
              const float* __restrict__ z_init, const float* __restrict__ sbuf,
              float* __restrict__ out)
{
  const int tid  = threadIdx.x;
  const int row  = tid >> 3, part = tid & 7;   // 32 paths per block
  const int b    = blockIdx.x * 32 + row;
  const float* xr = X + (size_t)b * ROWSTR;   // step 0
  const float* dr = DW + (size_t)b * ROWSTR;
  float p = 0.f;
#pragma unroll
  for (int g = part; g < 25; g += 8) {
    const float4 xv = *(const float4*)(xr + g*4);
    const float4 dv = *(const float4*)(dr + g*4);
    const float4 sg = *(const float4*)(sigmas + g*4);
    const float4 zv = *(const float4*)(z_init + g*4);
    p += sg.x*xv.x*zv.x*dv.x;
    p += sg.y*xv.y*zv.y*dv.y;
    p += sg.z*xv.z*zv.z*dv.z;
    p += sg.w*xv.w*zv.w*dv.w;
  }
  p += __shfl_xor(p, 1, 64);
  p += __shfl_xor(p, 2, 64);
  p += __shfl_xor(p, 4, 64);

  const float G = 1.f + R_C*DT_C;
  float ss = 0.f;
#pragma unroll
  for (int tau = 1 + part; tau < NSTEP; tau += 8)
    ss += sbuf[(size_t)tau*B_PATHS + b] * __powf(G, (float)(NSTEP - 1 - tau));
  ss += __shfl_xor(ss, 1, 64);
  ss += __shfl_xor(ss, 2, 64);
  ss += __shfl_xor(ss, 4, 64);

  if (part == 0)
    out[b] = y_init[0]*__powf(G, 30.f) + p*__powf(G, 29.f) + ss;
}

extern "C" void kernel_launch(void* const* d_in, const int* in_sizes, int n_in,
                              void* d_out, int out_size, void* d_ws, size_t ws_size,
                              hipStream_t stream) {
  const float* X      = (const float*)d_in[0];
  const float* DWs    = (const float*)d_in[1];
  const float* sigmas = (const float*)d_in[2];
  const float* y_init = (const float*)d_in[3];
  const float* z_init = (const float*)d_in[4];
  const float* W1     = (const float*)d_in[5];
  const float* W2     = (const float*)d_in[6];
  const float* W3     = (const float*)d_in[7];
  const float* bn[16];
  for (int i = 0; i < 16; ++i) bn[i] = (const float*)d_in[8 + i];

  char* ws = (char*)d_ws;
  ushort_t* wprep = (ushort_t*)ws;                     // 87*14336*2 = 2,494,464 B
  float*    bprep = (float*)(ws + 2494464);            // 87*128*4   =    44,544 B
  float*    sbuf  = (float*)(ws + 2539008);            // 30*8192*4  =   983,040 B
  float*    out   = (float*)d_out;

  prep_kernel<<<dim3(3, TT), 256, 0, stream>>>(
      W1, W2, W3,
      bn[0], bn[1], bn[2], bn[3],  bn[4], bn[5], bn[6], bn[7],
      bn[8], bn[9], bn[10], bn[11], bn[12], bn[13], bn[14], bn[15],
      wprep, bprep);
  subnet_kernel<<<dim3(B_PATHS/64, TT), 256, 0, stream>>>(
      X, DWs, sigmas, wprep, bprep, sbuf);
  y_kernel<<<dim3(B_PATHS/32), 256, 0, stream>>>(
      X, DWs, sigmas, y_init, z_init, sbuf, out);
}